// Round 1
// baseline (1829.856 us; speedup 1.0000x reference)
//
#include <hip/hip_runtime.h>
#include <cmath>

#define BB 16
#define TT 600
#define VV 20000
#define EE 300
#define HH 512

// workspace offsets in floats
#define OFF_KEYS_G 0
#define OFF_KEYS_C 4915200
#define OFF_X1     9830400   // 16*1324
#define OFF_QG     9851584
#define OFF_QC     9859776
#define OFF_SG     9867968   // scores/align g (16*600)
#define OFF_SC     9877568   // scores/align c
#define OFF_CTX    9887168   // 16*512
#define OFF_RMAX   9895360
#define OFF_RSUM   9895376
#define OFF_SW     9895392

__device__ __forceinline__ float sigmoidf_(float x) { return 1.0f / (1.0f + expf(-x)); }

// ---------------- build X1 = [emb | last_hidden_attn | h1]  (16 x 1324) ----------------
__global__ void k_build_x1(const int* __restrict__ x, const float* __restrict__ emb_table,
                           const float* __restrict__ lha, const float* __restrict__ h1,
                           float* __restrict__ X1) {
    int gid = blockIdx.x * 256 + threadIdx.x;
    if (gid >= BB * 1324) return;
    int b = gid / 1324, i = gid - b * 1324;
    float v;
    if (i < EE)            v = emb_table[(size_t)x[b] * EE + i];
    else if (i < EE + HH)  v = lha[b * HH + (i - EE)];
    else                   v = h1[b * HH + (i - EE - HH)];
    X1[gid] = v;
}

// ---------------- LSTM1: z = X1 @ [k1;r1] + b1 ----------------
__global__ __launch_bounds__(256) void k_lstm1(const float* __restrict__ X1,
        const float* __restrict__ k1, const float* __restrict__ r1, const float* __restrict__ b1,
        const float* __restrict__ c_old, float* __restrict__ h_new, float* __restrict__ c_new) {
    __shared__ float sx[1324];
    int gid = blockIdx.x * 256 + threadIdx.x;
    int b = gid >> 9, n = gid & 511;
    const float* xr = X1 + b * 1324;
    for (int i = threadIdx.x; i < 1324; i += 256) sx[i] = xr[i];
    __syncthreads();
    float ai = 0.f, af = 0.f, ag = 0.f, ao = 0.f;
    for (int i = 0; i < 1324; ++i) {
        const float* w = (i < 812) ? (k1 + (size_t)i * 2048) : (r1 + (size_t)(i - 812) * 2048);
        float xv = sx[i];
        ai += xv * w[n];
        af += xv * w[n + 512];
        ag += xv * w[n + 1024];
        ao += xv * w[n + 1536];
    }
    ai += b1[n]; af += b1[n + 512]; ag += b1[n + 1024]; ao += b1[n + 1536];
    float I = sigmoidf_(ai), F = sigmoidf_(af), G = tanhf(ag), O = sigmoidf_(ao);
    float c = F * c_old[b * 512 + n] + I * G;
    c_new[b * 512 + n] = c;
    h_new[b * 512 + n] = O * tanhf(c);
}

// ---------------- LSTM2: z = [h1n|h2] @ [k2;r2] + b2 ----------------
__global__ __launch_bounds__(256) void k_lstm2(const float* __restrict__ h1n,
        const float* __restrict__ h2, const float* __restrict__ k2, const float* __restrict__ r2,
        const float* __restrict__ b2, const float* __restrict__ c_old,
        float* __restrict__ h_new, float* __restrict__ c_new) {
    __shared__ float sx[1024];
    int gid = blockIdx.x * 256 + threadIdx.x;
    int b = gid >> 9, n = gid & 511;
    for (int i = threadIdx.x; i < 512; i += 256) {
        sx[i] = h1n[b * 512 + i];
        sx[512 + i] = h2[b * 512 + i];
    }
    __syncthreads();
    float ai = 0.f, af = 0.f, ag = 0.f, ao = 0.f;
    for (int i = 0; i < 1024; ++i) {
        const float* w = (i < 512) ? (k2 + (size_t)i * 2048) : (r2 + (size_t)(i - 512) * 2048);
        float xv = sx[i];
        ai += xv * w[n];
        af += xv * w[n + 512];
        ag += xv * w[n + 1024];
        ao += xv * w[n + 1536];
    }
    ai += b2[n]; af += b2[n + 512]; ag += b2[n + 1024]; ao += b2[n + 1536];
    float I = sigmoidf_(ai), F = sigmoidf_(af), G = tanhf(ag), O = sigmoidf_(ao);
    float c = F * c_old[b * 512 + n] + I * G;
    c_new[b * 512 + n] = c;
    h_new[b * 512 + n] = O * tanhf(c);
}

// ---------------- keys = enc_outs @ aw2{g,c}  (9600x512)@(512x512), fp32 tiled ----------------
__global__ __launch_bounds__(256) void k_keys_gemm(const float* __restrict__ A,
        const float* __restrict__ Wg_, const float* __restrict__ Wc_,
        float* __restrict__ keys_g, float* __restrict__ keys_c) {
    const float* W = (blockIdx.z == 0) ? Wg_ : Wc_;
    float* C = (blockIdx.z == 0) ? keys_g : keys_c;
    int m0 = blockIdx.x * 64;
    int n0 = blockIdx.y * 64;
    __shared__ float As[16][68];
    __shared__ float Bs[16][68];
    int tid = threadIdx.x;
    int tm = tid & 15, tn = tid >> 4;
    float acc[4][4] = {};
    for (int k0 = 0; k0 < 512; k0 += 16) {
        // A tile 64x16, transposed into As[k][m]; float4 along k
        {
            int m = tid >> 2, kq = tid & 3;
            float4 av = *(const float4*)&A[(size_t)(m0 + m) * 512 + k0 + 4 * kq];
            As[4 * kq + 0][m] = av.x;
            As[4 * kq + 1][m] = av.y;
            As[4 * kq + 2][m] = av.z;
            As[4 * kq + 3][m] = av.w;
        }
        // B tile 16x64
        {
            int n = tid & 63;
            for (int kk = tid >> 6; kk < 16; kk += 4)
                Bs[kk][n] = W[(size_t)(k0 + kk) * 512 + n0 + n];
        }
        __syncthreads();
#pragma unroll
        for (int k = 0; k < 16; ++k) {
            float4 a4 = *(const float4*)&As[k][4 * tm];
            float4 b4 = *(const float4*)&Bs[k][4 * tn];
            acc[0][0] += a4.x * b4.x; acc[0][1] += a4.x * b4.y; acc[0][2] += a4.x * b4.z; acc[0][3] += a4.x * b4.w;
            acc[1][0] += a4.y * b4.x; acc[1][1] += a4.y * b4.y; acc[1][2] += a4.y * b4.z; acc[1][3] += a4.y * b4.w;
            acc[2][0] += a4.z * b4.x; acc[2][1] += a4.z * b4.y; acc[2][2] += a4.z * b4.z; acc[2][3] += a4.z * b4.w;
            acc[3][0] += a4.w * b4.x; acc[3][1] += a4.w * b4.y; acc[3][2] += a4.w * b4.z; acc[3][3] += a4.w * b4.w;
        }
        __syncthreads();
    }
#pragma unroll
    for (int i = 0; i < 4; ++i) {
        float4 o;
        o.x = acc[i][0]; o.y = acc[i][1]; o.z = acc[i][2]; o.w = acc[i][3];
        *(float4*)&C[(size_t)(m0 + 4 * tm + i) * 512 + n0 + 4 * tn] = o;
    }
}

// ---------------- q = h2n @ aw1{g,c}  (16x512)@(512x512) ----------------
__global__ void k_qproj(const float* __restrict__ h2n, const float* __restrict__ aw1g,
                        const float* __restrict__ aw1c, float* __restrict__ qg, float* __restrict__ qc) {
    int gid = blockIdx.x * 256 + threadIdx.x;   // 16384 threads
    int variant = gid >> 13;
    int r = gid & 8191;
    int b = r >> 9, j = r & 511;
    const float* W = variant ? aw1c : aw1g;
    const float* h = h2n + b * 512;
    float acc = 0.f;
    for (int i = 0; i < 512; ++i) acc += h[i] * W[(size_t)i * 512 + j];
    (variant ? qc : qg)[b * 512 + j] = acc;
}

// ---------------- score[b,t] = sum_h tanh(q+key)*v ; one wave per (b,t,variant) ----------------
__global__ __launch_bounds__(256) void k_scores(const float* __restrict__ keys_g,
        const float* __restrict__ keys_c, const float* __restrict__ qg, const float* __restrict__ qc,
        const float* __restrict__ avg, const float* __restrict__ avc,
        float* __restrict__ sg, float* __restrict__ sc) {
    int gw = blockIdx.x * 4 + (threadIdx.x >> 6);
    int lane = threadIdx.x & 63;
    int variant = (gw >= BB * TT) ? 1 : 0;
    int r = variant ? (gw - BB * TT) : gw;
    int b = r / TT;
    const float* q = (variant ? qc : qg) + b * 512;
    const float* key = (variant ? keys_c : keys_g) + (size_t)r * 512;
    const float* v = variant ? avc : avg;
    float s = 0.f;
    for (int h = lane; h < 512; h += 64) s += tanhf(q[h] + key[h]) * v[h];
    for (int off = 32; off; off >>= 1) s += __shfl_down(s, off);
    if (lane == 0) (variant ? sc : sg)[r] = s;
}

// ---------------- softmax over T, in place ----------------
__global__ void k_softmax_t(float* __restrict__ sg, float* __restrict__ sc) {
    __shared__ float sv[TT];
    __shared__ float red[256];
    int b = blockIdx.x & 15, variant = blockIdx.x >> 4;
    float* s = (variant ? sc : sg) + b * TT;
    int tid = threadIdx.x;
    float m = -1e30f;
    for (int i = tid; i < TT; i += 256) { sv[i] = s[i]; m = fmaxf(m, sv[i]); }
    red[tid] = m; __syncthreads();
    for (int off = 128; off; off >>= 1) { if (tid < off) red[tid] = fmaxf(red[tid], red[tid + off]); __syncthreads(); }
    m = red[0]; __syncthreads();
    float sum = 0.f;
    for (int i = tid; i < TT; i += 256) { float e = expf(sv[i] - m); sv[i] = e; sum += e; }
    red[tid] = sum; __syncthreads();
    for (int off = 128; off; off >>= 1) { if (tid < off) red[tid] += red[tid + off]; __syncthreads(); }
    float inv = 1.0f / red[0];
    __syncthreads();
    for (int i = tid; i < TT; i += 256) s[i] = sv[i] * inv;
}

__global__ void k_zero_ctx(float* __restrict__ ctx) {
    int gid = blockIdx.x * 256 + threadIdx.x;
    if (gid < BB * HH) ctx[gid] = 0.f;
}

// ---------------- context[b,h] = sum_t align_g[b,t]*enc_outs[b,t,h], t split in 4 ----------------
__global__ void k_context(const float* __restrict__ align_g, const float* __restrict__ enc_outs,
                          float* __restrict__ ctx) {
    __shared__ float sa[150];
    int b = blockIdx.y, tc = blockIdx.x;
    int tid = threadIdx.x;  // 512
    if (tid < 150) sa[tid] = align_g[b * TT + tc * 150 + tid];
    __syncthreads();
    const float* e = enc_outs + (size_t)(b * TT + tc * 150) * 512 + tid;
    float acc = 0.f;
#pragma unroll 6
    for (int t = 0; t < 150; ++t) acc += sa[t] * e[(size_t)t * 512];
    atomicAdd(&ctx[b * 512 + tid], acc);
}

// ---------------- hidden_att = tanh([ctx|h2n] @ Wh + bh) ----------------
__global__ void k_hidden(const float* __restrict__ ctx, const float* __restrict__ h2n,
                         const float* __restrict__ Wh, const float* __restrict__ bh,
                         float* __restrict__ hid) {
    int gid = blockIdx.x * 256 + threadIdx.x;
    int b = gid >> 9, j = gid & 511;
    float acc = 0.f;
    for (int k = 0; k < 512; ++k) acc += ctx[b * 512 + k] * Wh[(size_t)k * 512 + j];
    for (int k = 0; k < 512; ++k) acc += h2n[b * 512 + k] * Wh[(size_t)(k + 512) * 512 + j];
    hid[b * 512 + j] = tanhf(acc + bh[j]);
}

// ---------------- switch = sigmoid(hid @ Wf + bf) ----------------
__global__ void k_switch(const float* __restrict__ hid, const float* __restrict__ Wf,
                         const float* __restrict__ bf, float* __restrict__ sw) {
    int b = threadIdx.x >> 6, lane = threadIdx.x & 63;  // 1024 threads = 16 waves
    float s = 0.f;
    for (int j = lane; j < 512; j += 64) s += hid[b * 512 + j] * Wf[j];
    for (int off = 32; off; off >>= 1) s += __shfl_down(s, off);
    if (lane == 0) sw[b] = sigmoidf_(s + bf[0]);
}

// ---------------- logits = hid @ Wg + bg -> d_out result region ----------------
__global__ __launch_bounds__(256) void k_logits(const float* __restrict__ hid,
        const float* __restrict__ Wg, const float* __restrict__ bg, float* __restrict__ out_logits) {
    __shared__ float sh[BB * HH];  // 32 KB
    int tid = threadIdx.x;
    for (int i = tid; i < BB * HH; i += 256) sh[i] = hid[i];
    __syncthreads();
    int v = blockIdx.x * 256 + tid;
    if (v >= VV) return;
    float acc[BB] = {};
#pragma unroll 4
    for (int k = 0; k < HH; ++k) {
        float w = Wg[(size_t)k * VV + v];
#pragma unroll
        for (int b = 0; b < BB; ++b) acc[b] += sh[b * HH + k] * w;
    }
    float bias = bg[v];
#pragma unroll
    for (int b = 0; b < BB; ++b) out_logits[(size_t)b * VV + v] = acc[b] + bias;
}

// ---------------- per-row max & sumexp over V ----------------
__global__ void k_softmax_v(const float* __restrict__ logits, float* __restrict__ rmax,
                            float* __restrict__ rsum) {
    __shared__ float red[1024];
    int b = blockIdx.x, tid = threadIdx.x;
    const float* l = logits + (size_t)b * VV;
    float m = -1e30f;
    for (int v = tid; v < VV; v += 1024) m = fmaxf(m, l[v]);
    red[tid] = m; __syncthreads();
    for (int off = 512; off; off >>= 1) { if (tid < off) red[tid] = fmaxf(red[tid], red[tid + off]); __syncthreads(); }
    m = red[0]; __syncthreads();
    float s = 0.f;
    for (int v = tid; v < VV; v += 1024) s += expf(l[v] - m);
    red[tid] = s; __syncthreads();
    for (int off = 512; off; off >>= 1) { if (tid < off) red[tid] += red[tid + off]; __syncthreads(); }
    if (tid == 0) { rmax[b] = m; rsum[b] = red[0]; }
}

// ---------------- result = softmax(logits)*(1-sw) + (align_c @ enc_ins)*sw ----------------
__global__ __launch_bounds__(256) void k_combine(const float* __restrict__ align_c,
        const float* __restrict__ enc_ins, const float* __restrict__ rmax,
        const float* __restrict__ rsum, const float* __restrict__ sw, float* __restrict__ out) {
    __shared__ float sa[TT];
    int b = blockIdx.y, tid = threadIdx.x;
    for (int i = tid; i < TT; i += 256) sa[i] = align_c[b * TT + i];
    __syncthreads();
    int v4 = blockIdx.x * 256 + tid;
    if (v4 >= VV / 4) return;
    const float4* e = (const float4*)enc_ins + (size_t)b * TT * (VV / 4) + v4;
    float4 a0 = {0, 0, 0, 0}, a1 = {0, 0, 0, 0}, a2 = {0, 0, 0, 0}, a3 = {0, 0, 0, 0};
    for (int t = 0; t < TT; t += 4) {
        float4 e0 = e[(size_t)(t + 0) * (VV / 4)];
        float4 e1 = e[(size_t)(t + 1) * (VV / 4)];
        float4 e2 = e[(size_t)(t + 2) * (VV / 4)];
        float4 e3 = e[(size_t)(t + 3) * (VV / 4)];
        float c0 = sa[t], c1 = sa[t + 1], c2 = sa[t + 2], c3 = sa[t + 3];
        a0.x += c0 * e0.x; a0.y += c0 * e0.y; a0.z += c0 * e0.z; a0.w += c0 * e0.w;
        a1.x += c1 * e1.x; a1.y += c1 * e1.y; a1.z += c1 * e1.z; a1.w += c1 * e1.w;
        a2.x += c2 * e2.x; a2.y += c2 * e2.y; a2.z += c2 * e2.z; a2.w += c2 * e2.w;
        a3.x += c3 * e3.x; a3.y += c3 * e3.y; a3.z += c3 * e3.z; a3.w += c3 * e3.w;
    }
    float4 cp;
    cp.x = a0.x + a1.x + a2.x + a3.x;
    cp.y = a0.y + a1.y + a2.y + a3.y;
    cp.z = a0.z + a1.z + a2.z + a3.z;
    cp.w = a0.w + a1.w + a2.w + a3.w;
    float m = rmax[b], inv = 1.0f / rsum[b], s = sw[b], os = 1.0f - s;
    float4* op = (float4*)(out + (size_t)b * VV) + v4;
    float4 l4 = *op;
    float4 r;
    r.x = expf(l4.x - m) * inv * os + cp.x * s;
    r.y = expf(l4.y - m) * inv * os + cp.y * s;
    r.z = expf(l4.z - m) * inv * os + cp.z * s;
    r.w = expf(l4.w - m) * inv * os + cp.w * s;
    *op = r;
}

extern "C" void kernel_launch(void* const* d_in, const int* in_sizes, int n_in,
                              void* d_out, int out_size, void* d_ws, size_t ws_size,
                              hipStream_t stream) {
    const int*   x        = (const int*)d_in[0];
    const float* lha      = (const float*)d_in[1];
    const float* h1       = (const float*)d_in[2];
    const float* c1       = (const float*)d_in[3];
    const float* h2       = (const float*)d_in[4];
    const float* c2       = (const float*)d_in[5];
    const float* enc_outs = (const float*)d_in[6];
    const float* enc_ins  = (const float*)d_in[7];
    const float* emb      = (const float*)d_in[8];
    const float* k1       = (const float*)d_in[9];
    const float* r1       = (const float*)d_in[10];
    const float* b1       = (const float*)d_in[11];
    const float* k2       = (const float*)d_in[12];
    const float* r2       = (const float*)d_in[13];
    const float* b2       = (const float*)d_in[14];
    const float* Wh       = (const float*)d_in[15];
    const float* bh       = (const float*)d_in[16];
    const float* Wg       = (const float*)d_in[17];
    const float* bg       = (const float*)d_in[18];
    const float* Wf       = (const float*)d_in[19];
    const float* bf       = (const float*)d_in[20];
    const float* aw1g     = (const float*)d_in[21];
    const float* aw2g     = (const float*)d_in[22];
    const float* avg      = (const float*)d_in[23];
    const float* aw1c     = (const float*)d_in[24];
    const float* aw2c     = (const float*)d_in[25];
    const float* avc      = (const float*)d_in[26];

    float* ws = (float*)d_ws;
    float* keys_g = ws + OFF_KEYS_G;
    float* keys_c = ws + OFF_KEYS_C;
    float* X1     = ws + OFF_X1;
    float* qg     = ws + OFF_QG;
    float* qc     = ws + OFF_QC;
    float* sg     = ws + OFF_SG;
    float* sc     = ws + OFF_SC;
    float* ctx    = ws + OFF_CTX;
    float* rmax   = ws + OFF_RMAX;
    float* rsum   = ws + OFF_RSUM;
    float* swbuf  = ws + OFF_SW;

    float* out     = (float*)d_out;
    float* out_res = out;                 // 16*20000
    float* out_hid = out + 320000;        // 16*512
    float* out_h1n = out + 328192;
    float* out_c1n = out + 336384;
    float* out_h2n = out + 344576;
    float* out_c2n = out + 352768;

    // Big independent GEMM first (keys for both attention heads)
    k_keys_gemm<<<dim3(150, 8, 2), 256, 0, stream>>>(enc_outs, aw2g, aw2c, keys_g, keys_c);

    // LSTM chain
    k_build_x1<<<(BB * 1324 + 255) / 256, 256, 0, stream>>>(x, emb, lha, h1, X1);
    k_lstm1<<<32, 256, 0, stream>>>(X1, k1, r1, b1, c1, out_h1n, out_c1n);
    k_lstm2<<<32, 256, 0, stream>>>(out_h1n, h2, k2, r2, b2, c2, out_h2n, out_c2n);

    // Attention
    k_qproj<<<64, 256, 0, stream>>>(out_h2n, aw1g, aw1c, qg, qc);
    k_scores<<<(2 * BB * TT) / 4, 256, 0, stream>>>(keys_g, keys_c, qg, qc, avg, avc, sg, sc);
    k_softmax_t<<<32, 256, 0, stream>>>(sg, sc);
    k_zero_ctx<<<32, 256, 0, stream>>>(ctx);
    k_context<<<dim3(4, BB), 512, 0, stream>>>(sg, enc_outs, ctx);

    // Output head
    k_hidden<<<32, 256, 0, stream>>>(ctx, out_h2n, Wh, bh, out_hid);
    k_switch<<<1, 1024, 0, stream>>>(out_hid, Wf, bf, swbuf);
    k_logits<<<(VV + 255) / 256, 256, 0, stream>>>(out_hid, Wg, bg, out_res);
    k_softmax_v<<<BB, 1024, 0, stream>>>(out_res, rmax, rsum);
    k_combine<<<dim3((VV / 4 + 255) / 256, BB), 256, 0, stream>>>(sc, enc_ins, rmax, rsum, swbuf, out_res);
}

// Round 2
// 1496.079 us; speedup vs baseline: 1.2231x; 1.2231x over previous
//
#include <hip/hip_runtime.h>
#include <cmath>

#define BB 16
#define TT 600
#define VV 20000
#define EE 300
#define HH 512

typedef unsigned short ushort_t;
using bf16x8 = __attribute__((ext_vector_type(8))) __bf16;
using f32x4  = __attribute__((ext_vector_type(4))) float;

// ---------------- workspace layout ----------------
// fp32 region (offsets in floats)
#define OFF_KEYS_G 0
#define OFF_KEYS_C 4915200
#define OFF_SG     9830400
#define OFF_SC     9840000
#define OFF_CTX    9849600
#define OFF_QG     9857792
#define OFF_QC     9865984
#define OFF_RMAX   9874176
#define OFF_RSUM   9874192
#define OFF_SW     9874208
#define OFF_BF     9874432   // bf16 region starts here (float offset)
// bf16 region (offsets in ushorts, relative to OFF_BF)
#define UOFF_ENCB   0
#define UOFF_WTAW2  4915200
#define UOFF_WTAW1  5439488
#define UOFF_WTH    5963776
#define UOFF_WT1    6488064   // 2048 x 1344
#define UOFF_WT2    9240576   // 2048 x 1024
#define UOFF_X1B    11337728  // 16 x 1344
#define UOFF_X2B    11359232  // 16 x 1024
#define UOFF_H2NB   11375616  // 16 x 512
#define UOFF_X3B    11383808  // 16 x 1024

__device__ __forceinline__ float sigmoidf_(float x) { return 1.0f / (1.0f + expf(-x)); }

__device__ __forceinline__ ushort_t f2bf(float f) {
    unsigned int u = __float_as_uint(f);
    u = (u + 0x7FFFu + ((u >> 16) & 1u)) >> 16;
    return (ushort_t)u;
}

__device__ __forceinline__ bf16x8 ldb(const ushort_t* p) {
    return *(const bf16x8*)(const void*)p;
}

// ---------------- cast enc_outs fp32 -> bf16 ----------------
__global__ __launch_bounds__(256) void k_cast_enc(const float* __restrict__ src,
                                                  ushort_t* __restrict__ dst, int n4) {
    int gid = blockIdx.x * 256 + threadIdx.x;
    if (gid >= n4) return;
    float4 v = ((const float4*)src)[gid];
    unsigned long long p = (unsigned long long)f2bf(v.x)
                         | ((unsigned long long)f2bf(v.y) << 16)
                         | ((unsigned long long)f2bf(v.z) << 32)
                         | ((unsigned long long)f2bf(v.w) << 48);
    *(unsigned long long*)(dst + (size_t)gid * 4) = p;
}

// ---------------- transpose + cast: out[n][k] = bf16(W[k][n]), W = [A;B] stacked, pad to Kp ----------------
__global__ __launch_bounds__(256) void k_tcast_pair(const float* __restrict__ A, int Ka,
        const float* __restrict__ Bsrc, int Kb, int N, int Kp, ushort_t* __restrict__ out) {
    __shared__ float tile[32][33];
    int nb = blockIdx.x * 32, kb = blockIdx.y * 32;
    int tid = threadIdx.x;
    int K = Ka + Kb;
    for (int kk = tid >> 5; kk < 32; kk += 8) {
        int k = kb + kk, n = nb + (tid & 31);
        float v = 0.f;
        if (k < Ka)      v = A[(size_t)k * N + n];
        else if (k < K)  v = Bsrc[(size_t)(k - Ka) * N + n];
        tile[kk][tid & 31] = v;
    }
    __syncthreads();
    for (int nn = tid >> 5; nn < 32; nn += 8) {
        int n = nb + nn, k = kb + (tid & 31);
        out[(size_t)n * Kp + k] = f2bf(tile[tid & 31][nn]);
    }
}

// ---------------- prep: X1b = bf16[emb|lha|h1|pad], X2b right half = bf16(h2) ----------------
__global__ __launch_bounds__(256) void k_prep(const int* __restrict__ x, const float* __restrict__ emb,
        const float* __restrict__ lha, const float* __restrict__ h1, const float* __restrict__ h2,
        ushort_t* __restrict__ X1b, ushort_t* __restrict__ X2b) {
    int gid = blockIdx.x * 256 + threadIdx.x;
    if (gid < BB * 1344) {
        int b = gid / 1344, i = gid - b * 1344;
        float v = 0.f;
        if (i < EE)             v = emb[(size_t)x[b] * EE + i];
        else if (i < EE + HH)   v = lha[b * HH + (i - EE)];
        else if (i < EE + 2*HH) v = h1[b * HH + (i - EE - HH)];
        X1b[gid] = f2bf(v);
    } else if (gid < BB * 1344 + BB * HH) {
        int r = gid - BB * 1344;
        int b = r >> 9, i = r & 511;
        X2b[b * 1024 + 512 + i] = f2bf(h2[b * HH + i]);
    }
}

// ---------------- keys = enc_outs @ aw2{g,c} via MFMA: (9600x512)@(512x512) ----------------
__global__ __launch_bounds__(256) void k_keys_mfma(const ushort_t* __restrict__ encb,
        const ushort_t* __restrict__ Wt_aw2, float* __restrict__ keys_g, float* __restrict__ keys_c) {
    int wave = threadIdx.x >> 6, lane = threadIdx.x & 63;
    int quad = lane >> 4, l16 = lane & 15;
    int m0 = (blockIdx.x * 4 + wave) * 16;
    int n0 = blockIdx.y * 64;
    const ushort_t* Wt = Wt_aw2 + (size_t)blockIdx.z * HH * HH;
    float* keys = blockIdx.z ? keys_c : keys_g;
    const ushort_t* arow = encb + (size_t)(m0 + l16) * HH + quad * 8;
    const ushort_t* brow = Wt + (size_t)(n0 + l16) * HH + quad * 8;
    f32x4 a0 = {0.f,0.f,0.f,0.f}, a1 = a0, a2 = a0, a3 = a0;
    for (int kk = 0; kk < HH; kk += 32) {
        bf16x8 a = ldb(arow + kk);
        a0 = __builtin_amdgcn_mfma_f32_16x16x32_bf16(a, ldb(brow + kk), a0, 0, 0, 0);
        a1 = __builtin_amdgcn_mfma_f32_16x16x32_bf16(a, ldb(brow + (size_t)16 * HH + kk), a1, 0, 0, 0);
        a2 = __builtin_amdgcn_mfma_f32_16x16x32_bf16(a, ldb(brow + (size_t)32 * HH + kk), a2, 0, 0, 0);
        a3 = __builtin_amdgcn_mfma_f32_16x16x32_bf16(a, ldb(brow + (size_t)48 * HH + kk), a3, 0, 0, 0);
    }
#pragma unroll
    for (int r = 0; r < 4; ++r) {
        int m = m0 + quad * 4 + r;
        keys[(size_t)m * HH + n0 + l16]      = a0[r];
        keys[(size_t)m * HH + n0 + 16 + l16] = a1[r];
        keys[(size_t)m * HH + n0 + 32 + l16] = a2[r];
        keys[(size_t)m * HH + n0 + 48 + l16] = a3[r];
    }
}

// ---------------- LSTM via MFMA, fused activation. z = Xb(16 x Kp) @ W(K x 2048) ----------------
__global__ __launch_bounds__(256) void k_lstm_mfma(const ushort_t* __restrict__ Xb,
        const ushort_t* __restrict__ Wt, int Kp, const float* __restrict__ bias,
        const float* __restrict__ c_old, float* __restrict__ h_new, float* __restrict__ c_new,
        ushort_t* __restrict__ hb, int hb_stride) {
    int wave = threadIdx.x >> 6, lane = threadIdx.x & 63;
    int quad = lane >> 4, l16 = lane & 15;
    int j0 = (blockIdx.x * 4 + wave) * 16;              // 0..496
    const ushort_t* arow = Xb + (size_t)l16 * Kp + quad * 8;
    const ushort_t* brow = Wt + (size_t)(j0 + l16) * Kp + quad * 8;
    f32x4 zi = {0.f,0.f,0.f,0.f}, zf = zi, zg = zi, zo = zi;
    for (int kk = 0; kk < Kp; kk += 32) {
        bf16x8 a = ldb(arow + kk);
        zi = __builtin_amdgcn_mfma_f32_16x16x32_bf16(a, ldb(brow + kk), zi, 0, 0, 0);
        zf = __builtin_amdgcn_mfma_f32_16x16x32_bf16(a, ldb(brow + (size_t)512 * Kp + kk), zf, 0, 0, 0);
        zg = __builtin_amdgcn_mfma_f32_16x16x32_bf16(a, ldb(brow + (size_t)1024 * Kp + kk), zg, 0, 0, 0);
        zo = __builtin_amdgcn_mfma_f32_16x16x32_bf16(a, ldb(brow + (size_t)1536 * Kp + kk), zo, 0, 0, 0);
    }
    int n = j0 + l16;
#pragma unroll
    for (int r = 0; r < 4; ++r) {
        int bi = quad * 4 + r;
        float I = sigmoidf_(zi[r] + bias[n]);
        float F = sigmoidf_(zf[r] + bias[512 + n]);
        float G = tanhf(zg[r] + bias[1024 + n]);
        float O = sigmoidf_(zo[r] + bias[1536 + n]);
        float c = F * c_old[bi * HH + n] + I * G;
        float h = O * tanhf(c);
        c_new[bi * HH + n] = c;
        h_new[bi * HH + n] = h;
        hb[(size_t)bi * hb_stride + n] = f2bf(h);
    }
}

// ---------------- q = h2n @ aw1{g,c} via MFMA ----------------
__global__ __launch_bounds__(256) void k_qproj_mfma(const ushort_t* __restrict__ h2nb,
        const ushort_t* __restrict__ Wt_aw1, float* __restrict__ qg, float* __restrict__ qc) {
    int wave = threadIdx.x >> 6, lane = threadIdx.x & 63;
    int quad = lane >> 4, l16 = lane & 15;
    int j0 = (blockIdx.x * 4 + wave) * 16;
    const ushort_t* Wt = Wt_aw1 + (size_t)blockIdx.y * HH * HH;
    float* q = blockIdx.y ? qc : qg;
    const ushort_t* arow = h2nb + (size_t)l16 * HH + quad * 8;
    const ushort_t* brow = Wt + (size_t)(j0 + l16) * HH + quad * 8;
    f32x4 acc = {0.f,0.f,0.f,0.f};
    for (int kk = 0; kk < HH; kk += 32)
        acc = __builtin_amdgcn_mfma_f32_16x16x32_bf16(ldb(arow + kk), ldb(brow + kk), acc, 0, 0, 0);
#pragma unroll
    for (int r = 0; r < 4; ++r)
        q[(quad * 4 + r) * HH + j0 + l16] = acc[r];
}

// ---------------- hidden = tanh(X3 @ Wh + bh) via MFMA, K=1024 ----------------
__global__ __launch_bounds__(256) void k_hidden_mfma(const ushort_t* __restrict__ X3b,
        const ushort_t* __restrict__ WtH, const float* __restrict__ bh, float* __restrict__ hid) {
    int wave = threadIdx.x >> 6, lane = threadIdx.x & 63;
    int quad = lane >> 4, l16 = lane & 15;
    int j0 = (blockIdx.x * 4 + wave) * 16;
    const ushort_t* arow = X3b + (size_t)l16 * 1024 + quad * 8;
    const ushort_t* brow = WtH + (size_t)(j0 + l16) * 1024 + quad * 8;
    f32x4 acc = {0.f,0.f,0.f,0.f};
    for (int kk = 0; kk < 1024; kk += 32)
        acc = __builtin_amdgcn_mfma_f32_16x16x32_bf16(ldb(arow + kk), ldb(brow + kk), acc, 0, 0, 0);
    int n = j0 + l16;
#pragma unroll
    for (int r = 0; r < 4; ++r)
        hid[(quad * 4 + r) * HH + n] = tanhf(acc[r] + bh[n]);
}

// ---------------- score[b,t] = sum_h tanh(q+key)*v ----------------
__global__ __launch_bounds__(256) void k_scores(const float* __restrict__ keys_g,
        const float* __restrict__ keys_c, const float* __restrict__ qg, const float* __restrict__ qc,
        const float* __restrict__ avg, const float* __restrict__ avc,
        float* __restrict__ sg, float* __restrict__ sc) {
    int gw = blockIdx.x * 4 + (threadIdx.x >> 6);
    int lane = threadIdx.x & 63;
    int variant = (gw >= BB * TT) ? 1 : 0;
    int r = variant ? (gw - BB * TT) : gw;
    int b = r / TT;
    const float* q = (variant ? qc : qg) + b * HH;
    const float* key = (variant ? keys_c : keys_g) + (size_t)r * HH;
    const float* v = variant ? avc : avg;
    float s = 0.f;
    for (int h = lane; h < HH; h += 64) s += tanhf(q[h] + key[h]) * v[h];
    for (int off = 32; off; off >>= 1) s += __shfl_down(s, off);
    if (lane == 0) (variant ? sc : sg)[r] = s;
}

// ---------------- softmax over T, in place ----------------
__global__ void k_softmax_t(float* __restrict__ sg, float* __restrict__ sc) {
    __shared__ float sv[TT];
    __shared__ float red[256];
    int b = blockIdx.x & 15, variant = blockIdx.x >> 4;
    float* s = (variant ? sc : sg) + b * TT;
    int tid = threadIdx.x;
    float m = -1e30f;
    for (int i = tid; i < TT; i += 256) { sv[i] = s[i]; m = fmaxf(m, sv[i]); }
    red[tid] = m; __syncthreads();
    for (int off = 128; off; off >>= 1) { if (tid < off) red[tid] = fmaxf(red[tid], red[tid + off]); __syncthreads(); }
    m = red[0]; __syncthreads();
    float sum = 0.f;
    for (int i = tid; i < TT; i += 256) { float e = expf(sv[i] - m); sv[i] = e; sum += e; }
    red[tid] = sum; __syncthreads();
    for (int off = 128; off; off >>= 1) { if (tid < off) red[tid] += red[tid + off]; __syncthreads(); }
    float inv = 1.0f / red[0];
    __syncthreads();
    for (int i = tid; i < TT; i += 256) s[i] = sv[i] * inv;
}

__global__ void k_zero_ctx(float* __restrict__ ctx) {
    int gid = blockIdx.x * 256 + threadIdx.x;
    if (gid < BB * HH) ctx[gid] = 0.f;
}

// ---------------- context[b,h] = sum_t align_g[b,t]*enc_outs[b,t,h] ----------------
__global__ void k_context(const float* __restrict__ align_g, const float* __restrict__ enc_outs,
                          float* __restrict__ ctx) {
    __shared__ float sa[150];
    int b = blockIdx.y, tc = blockIdx.x;
    int tid = threadIdx.x;  // 512
    if (tid < 150) sa[tid] = align_g[b * TT + tc * 150 + tid];
    __syncthreads();
    const float* e = enc_outs + (size_t)(b * TT + tc * 150) * HH + tid;
    float acc = 0.f;
#pragma unroll 6
    for (int t = 0; t < 150; ++t) acc += sa[t] * e[(size_t)t * HH];
    atomicAdd(&ctx[b * HH + tid], acc);
}

// ---------------- X3b = bf16[ctx | h2n] ----------------
__global__ __launch_bounds__(256) void k_ctxcast(const float* __restrict__ ctx,
        const float* __restrict__ h2n, ushort_t* __restrict__ X3b) {
    int gid = blockIdx.x * 256 + threadIdx.x;   // 16*1024
    int b = gid >> 10, i = gid & 1023;
    float v = (i < HH) ? ctx[b * HH + i] : h2n[b * HH + (i - HH)];
    X3b[gid] = f2bf(v);
}

// ---------------- switch = sigmoid(hid @ Wf + bf) ----------------
__global__ void k_switch(const float* __restrict__ hid, const float* __restrict__ Wf,
                         const float* __restrict__ bf, float* __restrict__ sw) {
    int b = threadIdx.x >> 6, lane = threadIdx.x & 63;
    float s = 0.f;
    for (int j = lane; j < HH; j += 64) s += hid[b * HH + j] * Wf[j];
    for (int off = 32; off; off >>= 1) s += __shfl_down(s, off);
    if (lane == 0) sw[b] = sigmoidf_(s + bf[0]);
}

// ---------------- logits = hid @ Wg + bg ----------------
__global__ __launch_bounds__(256) void k_logits(const float* __restrict__ hid,
        const float* __restrict__ Wg, const float* __restrict__ bg, float* __restrict__ out_logits) {
    __shared__ float sh[BB * HH];
    int tid = threadIdx.x;
    for (int i = tid; i < BB * HH; i += 256) sh[i] = hid[i];
    __syncthreads();
    int v = blockIdx.x * 256 + tid;
    if (v >= VV) return;
    float acc[BB] = {};
#pragma unroll 8
    for (int k = 0; k < HH; ++k) {
        float w = Wg[(size_t)k * VV + v];
#pragma unroll
        for (int b = 0; b < BB; ++b) acc[b] += sh[b * HH + k] * w;
    }
    float bias = bg[v];
#pragma unroll
    for (int b = 0; b < BB; ++b) out_logits[(size_t)b * VV + v] = acc[b] + bias;
}

// ---------------- per-row max & sumexp over V ----------------
__global__ void k_softmax_v(const float* __restrict__ logits, float* __restrict__ rmax,
                            float* __restrict__ rsum) {
    __shared__ float red[1024];
    int b = blockIdx.x, tid = threadIdx.x;
    const float* l = logits + (size_t)b * VV;
    float m = -1e30f;
    for (int v = tid; v < VV; v += 1024) m = fmaxf(m, l[v]);
    red[tid] = m; __syncthreads();
    for (int off = 512; off; off >>= 1) { if (tid < off) red[tid] = fmaxf(red[tid], red[tid + off]); __syncthreads(); }
    m = red[0]; __syncthreads();
    float s = 0.f;
    for (int v = tid; v < VV; v += 1024) s += expf(l[v] - m);
    red[tid] = s; __syncthreads();
    for (int off = 512; off; off >>= 1) { if (tid < off) red[tid] += red[tid + off]; __syncthreads(); }
    if (tid == 0) { rmax[b] = m; rsum[b] = red[0]; }
}

// ---------------- result = softmax(logits)*(1-sw) + (align_c @ enc_ins)*sw ----------------
__global__ __launch_bounds__(128) void k_combine(const float* __restrict__ align_c,
        const float* __restrict__ enc_ins, const float* __restrict__ rmax,
        const float* __restrict__ rsum, const float* __restrict__ sw, float* __restrict__ out) {
    __shared__ float sa[TT];
    int b = blockIdx.y, tid = threadIdx.x;
    for (int i = tid; i < TT; i += 128) sa[i] = align_c[b * TT + i];
    __syncthreads();
    int v4 = blockIdx.x * 128 + tid;
    if (v4 >= VV / 4) return;
    const float4* e = (const float4*)enc_ins + (size_t)b * TT * (VV / 4) + v4;
    float4 p0 = {0,0,0,0}, p1 = {0,0,0,0}, p2 = {0,0,0,0}, p3 = {0,0,0,0};
    for (int t = 0; t < TT; t += 8) {
        float4 e0 = e[(size_t)(t + 0) * (VV / 4)];
        float4 e1 = e[(size_t)(t + 1) * (VV / 4)];
        float4 e2 = e[(size_t)(t + 2) * (VV / 4)];
        float4 e3 = e[(size_t)(t + 3) * (VV / 4)];
        float4 e4 = e[(size_t)(t + 4) * (VV / 4)];
        float4 e5 = e[(size_t)(t + 5) * (VV / 4)];
        float4 e6 = e[(size_t)(t + 6) * (VV / 4)];
        float4 e7 = e[(size_t)(t + 7) * (VV / 4)];
        float c0 = sa[t], c1 = sa[t+1], c2 = sa[t+2], c3 = sa[t+3];
        float c4 = sa[t+4], c5 = sa[t+5], c6 = sa[t+6], c7 = sa[t+7];
        p0.x += c0*e0.x + c4*e4.x; p0.y += c0*e0.y + c4*e4.y; p0.z += c0*e0.z + c4*e4.z; p0.w += c0*e0.w + c4*e4.w;
        p1.x += c1*e1.x + c5*e5.x; p1.y += c1*e1.y + c5*e5.y; p1.z += c1*e1.z + c5*e5.z; p1.w += c1*e1.w + c5*e5.w;
        p2.x += c2*e2.x + c6*e6.x; p2.y += c2*e2.y + c6*e6.y; p2.z += c2*e2.z + c6*e6.z; p2.w += c2*e2.w + c6*e6.w;
        p3.x += c3*e3.x + c7*e7.x; p3.y += c3*e3.y + c7*e7.y; p3.z += c3*e3.z + c7*e7.z; p3.w += c3*e3.w + c7*e7.w;
    }
    float4 cp;
    cp.x = p0.x + p1.x + p2.x + p3.x;
    cp.y = p0.y + p1.y + p2.y + p3.y;
    cp.z = p0.z + p1.z + p2.z + p3.z;
    cp.w = p0.w + p1.w + p2.w + p3.w;
    float m = rmax[b], inv = 1.0f / rsum[b], s = sw[b], os = 1.0f - s;
    float4* op = (float4*)(out + (size_t)b * VV) + v4;
    float4 l4 = *op;
    float4 r;
    r.x = expf(l4.x - m) * inv * os + cp.x * s;
    r.y = expf(l4.y - m) * inv * os + cp.y * s;
    r.z = expf(l4.z - m) * inv * os + cp.z * s;
    r.w = expf(l4.w - m) * inv * os + cp.w * s;
    *op = r;
}

extern "C" void kernel_launch(void* const* d_in, const int* in_sizes, int n_in,
                              void* d_out, int out_size, void* d_ws, size_t ws_size,
                              hipStream_t stream) {
    const int*   x        = (const int*)d_in[0];
    const float* lha      = (const float*)d_in[1];
    const float* h1       = (const float*)d_in[2];
    const float* c1       = (const float*)d_in[3];
    const float* h2       = (const float*)d_in[4];
    const float* c2       = (const float*)d_in[5];
    const float* enc_outs = (const float*)d_in[6];
    const float* enc_ins  = (const float*)d_in[7];
    const float* emb      = (const float*)d_in[8];
    const float* k1       = (const float*)d_in[9];
    const float* r1       = (const float*)d_in[10];
    const float* b1       = (const float*)d_in[11];
    const float* k2       = (const float*)d_in[12];
    const float* r2       = (const float*)d_in[13];
    const float* b2       = (const float*)d_in[14];
    const float* Wh       = (const float*)d_in[15];
    const float* bh       = (const float*)d_in[16];
    const float* Wg       = (const float*)d_in[17];
    const float* bg       = (const float*)d_in[18];
    const float* Wf       = (const float*)d_in[19];
    const float* bf       = (const float*)d_in[20];
    const float* aw1g     = (const float*)d_in[21];
    const float* aw2g     = (const float*)d_in[22];
    const float* avg      = (const float*)d_in[23];
    const float* aw1c     = (const float*)d_in[24];
    const float* aw2c     = (const float*)d_in[25];
    const float* avc      = (const float*)d_in[26];

    float* ws = (float*)d_ws;
    float* keys_g = ws + OFF_KEYS_G;
    float* keys_c = ws + OFF_KEYS_C;
    float* sg     = ws + OFF_SG;
    float* sc     = ws + OFF_SC;
    float* ctx    = ws + OFF_CTX;
    float* qg     = ws + OFF_QG;
    float* qc     = ws + OFF_QC;
    float* rmax   = ws + OFF_RMAX;
    float* rsum   = ws + OFF_RSUM;
    float* swbuf  = ws + OFF_SW;
    ushort_t* wsb   = (ushort_t*)(ws + OFF_BF);
    ushort_t* encb  = wsb + UOFF_ENCB;
    ushort_t* WtA2  = wsb + UOFF_WTAW2;
    ushort_t* WtA1  = wsb + UOFF_WTAW1;
    ushort_t* WtH   = wsb + UOFF_WTH;
    ushort_t* Wt1   = wsb + UOFF_WT1;
    ushort_t* Wt2   = wsb + UOFF_WT2;
    ushort_t* X1b   = wsb + UOFF_X1B;
    ushort_t* X2b   = wsb + UOFF_X2B;
    ushort_t* h2nb  = wsb + UOFF_H2NB;
    ushort_t* X3b   = wsb + UOFF_X3B;

    float* out     = (float*)d_out;
    float* out_res = out;
    float* out_hid = out + 320000;
    float* out_h1n = out + 328192;
    float* out_c1n = out + 336384;
    float* out_h2n = out + 344576;
    float* out_c2n = out + 352768;

    // casts (independent)
    k_cast_enc<<<4800, 256, 0, stream>>>(enc_outs, encb, BB * TT * HH / 4);
    k_tcast_pair<<<dim3(16, 16), 256, 0, stream>>>(aw2g, 512, nullptr, 0, 512, 512, WtA2);
    k_tcast_pair<<<dim3(16, 16), 256, 0, stream>>>(aw2c, 512, nullptr, 0, 512, 512, WtA2 + 262144);
    k_tcast_pair<<<dim3(16, 16), 256, 0, stream>>>(aw1g, 512, nullptr, 0, 512, 512, WtA1);
    k_tcast_pair<<<dim3(16, 16), 256, 0, stream>>>(aw1c, 512, nullptr, 0, 512, 512, WtA1 + 262144);
    k_tcast_pair<<<dim3(16, 32), 256, 0, stream>>>(Wh, 1024, nullptr, 0, 512, 1024, WtH);
    k_tcast_pair<<<dim3(64, 42), 256, 0, stream>>>(k1, 812, r1, 512, 2048, 1344, Wt1);
    k_tcast_pair<<<dim3(64, 32), 256, 0, stream>>>(k2, 512, r2, 512, 2048, 1024, Wt2);
    k_prep<<<116, 256, 0, stream>>>(x, emb, lha, h1, h2, X1b, X2b);

    // keys GEMM (MFMA)
    k_keys_mfma<<<dim3(150, 8, 2), 256, 0, stream>>>(encb, WtA2, keys_g, keys_c);

    // LSTM chain (MFMA, fused activation)
    k_lstm_mfma<<<8, 256, 0, stream>>>(X1b, Wt1, 1344, b1, c1, out_h1n, out_c1n, X2b, 1024);
    k_lstm_mfma<<<8, 256, 0, stream>>>(X2b, Wt2, 1024, b2, c2, out_h2n, out_c2n, h2nb, 512);

    // attention
    k_qproj_mfma<<<dim3(8, 2), 256, 0, stream>>>(h2nb, WtA1, qg, qc);
    k_scores<<<(2 * BB * TT) / 4, 256, 0, stream>>>(keys_g, keys_c, qg, qc, avg, avc, sg, sc);
    k_softmax_t<<<32, 256, 0, stream>>>(sg, sc);
    k_zero_ctx<<<32, 256, 0, stream>>>(ctx);
    k_context<<<dim3(4, BB), 512, 0, stream>>>(sg, enc_outs, ctx);
    k_ctxcast<<<64, 256, 0, stream>>>(ctx, out_h2n, X3b);

    // output head
    k_hidden_mfma<<<8, 256, 0, stream>>>(X3b, WtH, bh, out_hid);
    k_switch<<<1, 1024, 0, stream>>>(out_hid, Wf, bf, swbuf);
    k_logits<<<(VV + 255) / 256, 256, 0, stream>>>(out_hid, Wg, bg, out_res);
    k_softmax_v<<<BB, 1024, 0, stream>>>(out_res, rmax, rsum);
    k_combine<<<dim3(40, BB), 128, 0, stream>>>(sc, enc_ins, rmax, rsum, swbuf, out_res);
}